// Round 10
// baseline (274.792 us; speedup 1.0000x reference)
//
#include <hip/hip_runtime.h>

// TCN, last-timestep receptive-field cone. 5 launches, NO split-K reduces:
//   K1: L0 conv (x->B1) + down conv (x->PDs), full-K, block-role split
//   K2: L1 conv (B1->H0, fused +PDs residual +relus)
//   K3: L2 conv (H0->B2)
//   K4: L3 conv (B2->H1, fused +H0[t=1023] residual +relus)
//   K5: fc (round-9 verbatim)
// Block = 256 thr = 16 slots (8 oc x 2 K-halves) x 16 batches; grid per conv
// = 64 ocp x 4 bq = 256 blocks. Intra-block K-reduce via LDS (deterministic).
// Activations stored [c][u][64 b]:
//   B1 [512][11][64] (u: t=1013+u), PDs [512][5][64] (down+bd0, t=1015+2u),
//   H0 [512][5][64] (t=1015+2u), B2 [512][3][64] (t=1019+2u), H1 [512][64].
// t-maps (verified vs round-4): L0 u=t+kk; down u=t (XBASE=4,XSTEP=2);
// L1 u=2t+kk; L2 u=t+kk; L3 u=kk; L3 residual = H0 u=4 (t=1023).

#define OUTD 36

// EPI: 0 = relu(acc+bias); 1 = acc+bias; 2 = relu(relu(acc+bias)+res)
template <int CIN, int TIN, int TOUT, int S, int DD, int TAPS,
          bool SRC_X, int XBASE, int XSTEP, int SRCPITCH,
          int EPI, int RESPITCH, int RESBASE, int RESSTEP, int OUTPITCH>
__device__ __forceinline__ void convfk(
    int ocp, int bq, const float* __restrict__ src, const float* __restrict__ w,
    const float* __restrict__ bias, const float* __restrict__ res,
    float* __restrict__ out, float* smem) {
  const int tid = threadIdx.x;
  const int lb = tid & 15, s = tid >> 4, oc_l = s & 7, ch = s >> 3;
  const int oc = ocp * 8 + oc_l;
  constexpr int CHALF = CIN / 2;
  constexpr int NCH = CHALF / 16;
  constexpr int XSZ = TIN * 16 * 17;  // per-half [TIN u][16 b][17 c]
  constexpr int BSZ = 16 * TIN * 16;  // per-half [16 c][TIN u][16 b]
  constexpr int WSZ = 16 * TAPS * 8;  // per-half [16 c][TAPS][8 oc]
  constexpr int ASZ = SRC_X ? XSZ : BSZ;
  float* Wl = smem + 2 * ASZ;
  float* Rl = Wl + 2 * WSZ;

  float acc[TOUT];
#pragma unroll
  for (int t = 0; t < TOUT; ++t) acc[t] = 0.f;

  for (int i = 0; i < NCH; ++i) {
    if (i) __syncthreads();
    // ---- stage activations for BOTH K-halves ----
    if constexpr (SRC_X) {
      for (int idx = tid; idx < 2 * 16 * TIN * 16; idx += 256) {
        int h = idx / (16 * TIN * 16), r = idx % (16 * TIN * 16);
        int c = r & 15, b = (r >> 4) & 15, u = r >> 8;
        smem[h * XSZ + (u * 16 + b) * 17 + c] =
            src[((size_t)(bq * 16 + b) * 1024 + 1011 + XBASE + XSTEP * u) * 256 +
                h * CHALF + i * 16 + c];
      }
    } else {
      for (int idx = tid; idx < 2 * 16 * TIN * 16; idx += 256) {
        int h = idx / (16 * TIN * 16), r = idx % (16 * TIN * 16);
        int b = r & 15, u = (r >> 4) % TIN, c = r / (16 * TIN);
        smem[h * BSZ + (c * TIN + u) * 16 + b] =
            src[(size_t)(h * CHALF + i * 16 + c) * SRCPITCH + u * 64 +
                bq * 16 + b];
      }
    }
    // ---- stage weights for BOTH K-halves ----
    for (int idx = tid; idx < 2 * 16 * TAPS * 8; idx += 256) {
      int s8 = idx & 7, kk = (idx >> 3) % TAPS;
      int c = (idx / (8 * TAPS)) & 15, h = idx / (8 * TAPS * 16);
      Wl[h * WSZ + (c * TAPS + kk) * 8 + s8] =
          w[(size_t)(ocp * 8 + s8) * (CIN * TAPS) +
            (h * CHALF + i * 16 + c) * TAPS + kk];
    }
    __syncthreads();
    // ---- compute: this slot's K-half ----
    for (int c = 0; c < 16; ++c) {
      float bv[TIN];
#pragma unroll
      for (int u = 0; u < TIN; ++u) {
        if constexpr (SRC_X)
          bv[u] = smem[ch * XSZ + (u * 16 + lb) * 17 + c];
        else
          bv[u] = smem[ch * BSZ + (c * TIN + u) * 16 + lb];
      }
      float wq[TAPS];
#pragma unroll
      for (int kk = 0; kk < TAPS; ++kk)
        wq[kk] = Wl[ch * WSZ + (c * TAPS + kk) * 8 + oc_l];
#pragma unroll
      for (int t = 0; t < TOUT; ++t)
#pragma unroll
        for (int kk = 0; kk < TAPS; ++kk)
          acc[t] += wq[kk] * bv[S * t + DD * kk];
    }
  }
  // ---- intra-block 2-way K reduce + epilogue (fixed order, deterministic) --
  if (ch == 1) {
#pragma unroll
    for (int t = 0; t < TOUT; ++t) Rl[(oc_l * TOUT + t) * 16 + lb] = acc[t];
  }
  __syncthreads();
  if (ch == 0) {
    const float bb = bias[oc];
#pragma unroll
    for (int t = 0; t < TOUT; ++t) {
      float v = acc[t] + Rl[(oc_l * TOUT + t) * 16 + lb];
      if constexpr (EPI == 0) {
        v = fmaxf(v + bb, 0.f);
      } else if constexpr (EPI == 1) {
        v = v + bb;
      } else {
        v = fmaxf(v + bb, 0.f);
        v += res[(size_t)oc * RESPITCH + RESBASE + t * RESSTEP + bq * 16 + lb];
        v = fmaxf(v, 0.f);
      }
      out[(size_t)oc * OUTPITCH + t * 64 + bq * 16 + lb] = v;
    }
  }
}

// K1: blocks 0..255 -> L0 (x->B1); 256..511 -> down (x->PDs, bias no relu)
__global__ __launch_bounds__(256) void k1(const float* __restrict__ x,
                                          const float* __restrict__ w1_0,
                                          const float* __restrict__ b1_0,
                                          const float* __restrict__ wd0,
                                          const float* __restrict__ bd0,
                                          float* __restrict__ B1,
                                          float* __restrict__ PDs) {
  __shared__ float smem[9248];  // L0: 2*3536 + 2*384 + 1408 = 9248
  const int bid = blockIdx.x;
  if (bid < 256) {
    convfk<256, 13, 11, 1, 1, 3, true, 0, 1, 0, 0, 0, 0, 0, 704>(
        bid >> 2, bid & 3, x, w1_0, b1_0, nullptr, B1, smem);
  } else {
    const int q = bid - 256;
    convfk<256, 5, 5, 1, 0, 1, true, 4, 2, 0, 1, 0, 0, 0, 320>(
        q >> 2, q & 3, x, wd0, bd0, nullptr, PDs, smem);
  }
}

// K2: L1 (B1->H0), residual = PDs (already含 bd0), t-step residual
__global__ __launch_bounds__(256) void k2(const float* __restrict__ B1,
                                          const float* __restrict__ w2_0,
                                          const float* __restrict__ b2_0,
                                          const float* __restrict__ PDs,
                                          float* __restrict__ H0) {
  __shared__ float smem[7040];  // 2*2816 + 2*384 + 640
  convfk<512, 11, 5, 2, 1, 3, false, 0, 0, 704, 2, 320, 0, 64, 320>(
      blockIdx.x >> 2, blockIdx.x & 3, B1, w2_0, b2_0, PDs, H0, smem);
}

// K3: L2 (H0->B2)
__global__ __launch_bounds__(256) void k3(const float* __restrict__ H0,
                                          const float* __restrict__ w1_1,
                                          const float* __restrict__ b1_1,
                                          float* __restrict__ B2) {
  __shared__ float smem[3712];  // 2*1280 + 2*384 + 384
  convfk<512, 5, 3, 1, 1, 3, false, 0, 0, 320, 0, 0, 0, 0, 192>(
      blockIdx.x >> 2, blockIdx.x & 3, H0, w1_1, b1_1, nullptr, B2, smem);
}

// K4: L3 (B2->H1), residual = H0 at u=4 (t=1023)
__global__ __launch_bounds__(256) void k4(const float* __restrict__ B2,
                                          const float* __restrict__ w2_1,
                                          const float* __restrict__ b2_1,
                                          const float* __restrict__ H0,
                                          float* __restrict__ H1) {
  __shared__ float smem[2432];  // 2*768 + 2*384 + 128
  convfk<512, 3, 1, 1, 1, 3, false, 0, 0, 192, 2, 320, 256, 0, 64>(
      blockIdx.x >> 2, blockIdx.x & 3, B2, w2_1, b2_1, H0, H1, smem);
}

// K5: fc (round-9 verbatim)
__global__ __launch_bounds__(64) void k_fc(const float* __restrict__ H1,
                                           const float* __restrict__ fcw,
                                           const float* __restrict__ fcb,
                                           float* __restrict__ out) {
  const int j = blockIdx.x, lane = threadIdx.x;
  float acc = fcb[j];
#pragma unroll 8
  for (int o = 0; o < 512; ++o) acc += fcw[j * 512 + o] * H1[o * 64 + lane];
  out[lane * OUTD + j] = acc;
}

extern "C" void kernel_launch(void* const* d_in, const int* in_sizes, int n_in,
                              void* d_out, int out_size, void* d_ws, size_t ws_size,
                              hipStream_t stream) {
  const float* x    = (const float*)d_in[0];
  const float* w1_0 = (const float*)d_in[4];
  const float* b1_0 = (const float*)d_in[5];
  const float* w2_0 = (const float*)d_in[6];
  const float* b2_0 = (const float*)d_in[7];
  const float* wd0  = (const float*)d_in[8];
  const float* bd0  = (const float*)d_in[9];
  const float* w1_1 = (const float*)d_in[10];
  const float* b1_1 = (const float*)d_in[11];
  const float* w2_1 = (const float*)d_in[12];
  const float* b2_1 = (const float*)d_in[13];
  const float* fcw  = (const float*)d_in[14];
  const float* fcb  = (const float*)d_in[15];
  float* out = (float*)d_out;

  float* B1  = (float*)d_ws;       // 512*11*64 = 360448
  float* PDs = B1 + 360448;        // 512*5*64  = 163840
  float* H0  = PDs + 163840;       // 512*5*64  = 163840
  float* B2  = H0 + 163840;        // 512*3*64  =  98304
  float* H1  = B2 + 98304;         // 512*64    =  32768

  k1<<<512, 256, 0, stream>>>(x, w1_0, b1_0, wd0, bd0, B1, PDs);
  k2<<<256, 256, 0, stream>>>(B1, w2_0, b2_0, PDs, H0);
  k3<<<256, 256, 0, stream>>>(H0, w1_1, b1_1, B2);
  k4<<<256, 256, 0, stream>>>(B2, w2_1, b2_1, H0, H1);
  k_fc<<<OUTD, 64, 0, stream>>>(H1, fcw, fcb, out);
}

// Round 11
// 124.617 us; speedup vs baseline: 2.2051x; 2.2051x over previous
//
#include <hip/hip_runtime.h>

// TCN, last-timestep receptive-field cone. 6 dispatches:
//   memset(acc)  -> kA: L0+down convs (split-K, atomicAdd into B1a/PDa)
//   kB: L1 conv  (staging finalizes B1 = relu(B1a+b1_0); atomicAdd H0a)
//   kC: L2 conv  (staging finalizes H0 = relu(relu(H0a+b2_0)+PDa+bd0); -> B2a)
//   kD: L3 conv  (staging finalizes B2 = relu(B2a+b1_1); atomicAdd H1a)
//   kE: fc       (finalizes H1 = relu(relu(H1a+b2_1)+H0fin[u=4]) inline)
// Accumulators (pre-bias conv sums), layout [c][u][64 b]:
//   B1a [512][11][64] t=1013+u   PDa [512][5][64] t=1015+2u (down, no bias)
//   H0a [512][5][64]  t=1015+2u  B2a [512][3][64] t=1019+2u  H1a [512][64]
// t-maps (verified round-10, absmax 1e-6): L0 u=t+kk; down u=t;
//   L1 u=2t+kk; L2 u=t+kk; L3 u=kk; residuals at H0 u=4 (t=1023).
// Conv blocks: 256 thr = 4 waves; lane = batch (64, fully coalesced);
// wave = oc quarter. Split-K over blockIdx ks; partial sums combined by
// fp32 atomicAdd (order jitter ~1e-6 << 2.3e-2 threshold).

__device__ __forceinline__ float relu(float v) { return fmaxf(v, 0.f); }

// ===== kA: blocks 0..255 L0 (32 ocp x 8 ks), 256..383 down (16 x 8) =======
__global__ __launch_bounds__(256) void kA(const float* __restrict__ x,
                                          const float* __restrict__ w1_0,
                                          const float* __restrict__ wd0,
                                          float* __restrict__ B1a,
                                          float* __restrict__ PDa) {
  __shared__ float smem[14080];  // L0: 768 W + 13312 X = 14080 w (56.3 KB)
  const int tid = threadIdx.x, lane = tid & 63, wv = tid >> 6;
  if (blockIdx.x < 256) {
    const int ocp = blockIdx.x >> 3, ks = blockIdx.x & 7, oc0 = ocp * 16;
    float* Als = smem;        // [16c][3kk][16oc]
    float* Bls = smem + 768;  // [(c*64+b)*13+u]
    float acc[4][11];
#pragma unroll
    for (int i = 0; i < 4; ++i)
#pragma unroll
      for (int t = 0; t < 11; ++t) acc[i][t] = 0.f;
    for (int ch = 0; ch < 2; ++ch) {
      const int c0 = ks * 32 + ch * 16;
      if (ch) __syncthreads();
      for (int idx = tid; idx < 768; idx += 256) {
        int i = idx / 48, r = idx % 48, c = r / 3, kk = r % 3;
        Als[(c * 3 + kk) * 16 + i] = w1_0[(oc0 + i) * 768 + (c0 + c) * 3 + kk];
      }
      for (int idx = tid; idx < 13312; idx += 256) {
        int c = idx & 15, b = (idx >> 4) & 63, u = idx >> 10;
        Bls[(c * 64 + b) * 13 + u] = x[(b * 1024 + 1011 + u) * 256 + c0 + c];
      }
      __syncthreads();
      for (int c = 0; c < 16; ++c) {
        float bv[13];
#pragma unroll
        for (int u = 0; u < 13; ++u) bv[u] = Bls[(c * 64 + lane) * 13 + u];
        float av[3][4];
#pragma unroll
        for (int kk = 0; kk < 3; ++kk)
          *(float4*)av[kk] = *(const float4*)&Als[(c * 3 + kk) * 16 + wv * 4];
#pragma unroll
        for (int i = 0; i < 4; ++i)
#pragma unroll
          for (int t = 0; t < 11; ++t)
#pragma unroll
            for (int kk = 0; kk < 3; ++kk)
              acc[i][t] += av[kk][i] * bv[t + kk];
      }
    }
#pragma unroll
    for (int i = 0; i < 4; ++i)
#pragma unroll
      for (int t = 0; t < 11; ++t)
        atomicAdd(&B1a[((oc0 + wv * 4 + i) * 11 + t) * 64 + lane], acc[i][t]);
  } else {
    const int q = blockIdx.x - 256;
    const int ocp = q >> 3, ks = q & 7, oc0 = ocp * 32;
    float* Ad = smem;        // [16c][32oc]
    float* Bd = smem + 512;  // [(c*64+b)*5+u]
    float acc[8][5];
#pragma unroll
    for (int i = 0; i < 8; ++i)
#pragma unroll
      for (int t = 0; t < 5; ++t) acc[i][t] = 0.f;
    for (int ch = 0; ch < 2; ++ch) {
      const int c0 = ks * 32 + ch * 16;
      if (ch) __syncthreads();
      for (int idx = tid; idx < 512; idx += 256) {
        int i = idx & 31, c = idx >> 5;
        Ad[c * 32 + i] = wd0[(oc0 + i) * 256 + c0 + c];
      }
      for (int idx = tid; idx < 5120; idx += 256) {
        int c = idx & 15, b = (idx >> 4) & 63, u = idx >> 10;
        Bd[(c * 64 + b) * 5 + u] = x[(b * 1024 + 1015 + 2 * u) * 256 + c0 + c];
      }
      __syncthreads();
      for (int c = 0; c < 16; ++c) {
        float bv[5];
#pragma unroll
        for (int u = 0; u < 5; ++u) bv[u] = Bd[(c * 64 + lane) * 5 + u];
        float av[8];
        *(float4*)&av[0] = *(const float4*)&Ad[c * 32 + wv * 8];
        *(float4*)&av[4] = *(const float4*)&Ad[c * 32 + wv * 8 + 4];
#pragma unroll
        for (int i = 0; i < 8; ++i)
#pragma unroll
          for (int t = 0; t < 5; ++t) acc[i][t] += av[i] * bv[t];
      }
    }
#pragma unroll
    for (int i = 0; i < 8; ++i)
#pragma unroll
      for (int t = 0; t < 5; ++t)
        atomicAdd(&PDa[((oc0 + wv * 8 + i) * 5 + t) * 64 + lane], acc[i][t]);
  }
}

// ===== kB: L1 conv (16 ocp x 16 ks), stage = relu(B1a+b1_0) ================
__global__ __launch_bounds__(256) void kB(const float* __restrict__ B1a,
                                          const float* __restrict__ b1_0,
                                          const float* __restrict__ w2_0,
                                          float* __restrict__ H0a) {
  __shared__ float smem[12800];  // 1536 W + 11264 B (51.2 KB)
  const int tid = threadIdx.x, lane = tid & 63, wv = tid >> 6;
  const int ocp = blockIdx.x >> 4, ks = blockIdx.x & 15, oc0 = ocp * 32;
  float* Als = smem;         // [16c][3kk][32oc]
  float* Bls = smem + 1536;  // [(c*11+u)*64+b]
  float acc[8][5];
#pragma unroll
  for (int i = 0; i < 8; ++i)
#pragma unroll
    for (int t = 0; t < 5; ++t) acc[i][t] = 0.f;
  for (int ch = 0; ch < 2; ++ch) {
    const int c0 = ks * 32 + ch * 16;
    if (ch) __syncthreads();
    for (int idx = tid; idx < 1536; idx += 256) {
      int i = idx / 48, r = idx % 48, c = r / 3, kk = r % 3;
      Als[(c * 3 + kk) * 32 + i] = w2_0[(oc0 + i) * 1536 + (c0 + c) * 3 + kk];
    }
    for (int idx = tid; idx < 11264; idx += 256) {
      int b = idx & 63, u = (idx >> 6) % 11, c = (idx >> 6) / 11;
      Bls[(c * 11 + u) * 64 + b] =
          relu(B1a[((c0 + c) * 11 + u) * 64 + b] + b1_0[c0 + c]);
    }
    __syncthreads();
    for (int c = 0; c < 16; ++c) {
      float bv[11];
#pragma unroll
      for (int u = 0; u < 11; ++u) bv[u] = Bls[(c * 11 + u) * 64 + lane];
      float av[3][8];
#pragma unroll
      for (int kk = 0; kk < 3; ++kk) {
        *(float4*)&av[kk][0] = *(const float4*)&Als[(c * 3 + kk) * 32 + wv * 8];
        *(float4*)&av[kk][4] =
            *(const float4*)&Als[(c * 3 + kk) * 32 + wv * 8 + 4];
      }
#pragma unroll
      for (int i = 0; i < 8; ++i)
#pragma unroll
        for (int t = 0; t < 5; ++t)
#pragma unroll
          for (int kk = 0; kk < 3; ++kk)
            acc[i][t] += av[kk][i] * bv[2 * t + kk];
    }
  }
#pragma unroll
  for (int i = 0; i < 8; ++i)
#pragma unroll
    for (int t = 0; t < 5; ++t)
      atomicAdd(&H0a[((oc0 + wv * 8 + i) * 5 + t) * 64 + lane], acc[i][t]);
}

// ===== kC: L2 conv (16 x 16), stage = relu(relu(H0a+b2_0)+PDa+bd0) =========
__global__ __launch_bounds__(256) void kC(const float* __restrict__ H0a,
                                          const float* __restrict__ b2_0,
                                          const float* __restrict__ PDa,
                                          const float* __restrict__ bd0,
                                          const float* __restrict__ w1_1,
                                          float* __restrict__ B2a) {
  __shared__ float smem[6656];  // 1536 W + 5120 B
  const int tid = threadIdx.x, lane = tid & 63, wv = tid >> 6;
  const int ocp = blockIdx.x >> 4, ks = blockIdx.x & 15, oc0 = ocp * 32;
  float* Als = smem;
  float* Bls = smem + 1536;  // [(c*5+u)*64+b]
  float acc[8][3];
#pragma unroll
  for (int i = 0; i < 8; ++i)
#pragma unroll
    for (int t = 0; t < 3; ++t) acc[i][t] = 0.f;
  for (int ch = 0; ch < 2; ++ch) {
    const int c0 = ks * 32 + ch * 16;
    if (ch) __syncthreads();
    for (int idx = tid; idx < 1536; idx += 256) {
      int i = idx / 48, r = idx % 48, c = r / 3, kk = r % 3;
      Als[(c * 3 + kk) * 32 + i] = w1_1[(oc0 + i) * 1536 + (c0 + c) * 3 + kk];
    }
    for (int idx = tid; idx < 5120; idx += 256) {
      int b = idx & 63, u = (idx >> 6) % 5, c = (idx >> 6) / 5;
      int cc = c0 + c;
      float v = relu(H0a[(cc * 5 + u) * 64 + b] + b2_0[cc]);
      Bls[(c * 5 + u) * 64 + b] = relu(v + PDa[(cc * 5 + u) * 64 + b] + bd0[cc]);
    }
    __syncthreads();
    for (int c = 0; c < 16; ++c) {
      float bv[5];
#pragma unroll
      for (int u = 0; u < 5; ++u) bv[u] = Bls[(c * 5 + u) * 64 + lane];
      float av[3][8];
#pragma unroll
      for (int kk = 0; kk < 3; ++kk) {
        *(float4*)&av[kk][0] = *(const float4*)&Als[(c * 3 + kk) * 32 + wv * 8];
        *(float4*)&av[kk][4] =
            *(const float4*)&Als[(c * 3 + kk) * 32 + wv * 8 + 4];
      }
#pragma unroll
      for (int i = 0; i < 8; ++i)
#pragma unroll
        for (int t = 0; t < 3; ++t)
#pragma unroll
          for (int kk = 0; kk < 3; ++kk)
            acc[i][t] += av[kk][i] * bv[t + kk];
    }
  }
#pragma unroll
  for (int i = 0; i < 8; ++i)
#pragma unroll
    for (int t = 0; t < 3; ++t)
      atomicAdd(&B2a[((oc0 + wv * 8 + i) * 3 + t) * 64 + lane], acc[i][t]);
}

// ===== kD: L3 conv (16 ocp x 16 ks, CCH=32, 1 phase), stage=relu(B2a+b1_1) =
__global__ __launch_bounds__(256) void kD(const float* __restrict__ B2a,
                                          const float* __restrict__ b1_1,
                                          const float* __restrict__ w2_1,
                                          float* __restrict__ H1a) {
  __shared__ float smem[9216];  // 3072 W + 6144 B
  const int tid = threadIdx.x, lane = tid & 63, wv = tid >> 6;
  const int ocp = blockIdx.x >> 4, ks = blockIdx.x & 15, oc0 = ocp * 32;
  const int c0 = ks * 32;
  float* Als = smem;         // [32c][3kk][32oc]
  float* Bls = smem + 3072;  // [(c*3+u)*64+b]
  float acc[8];
#pragma unroll
  for (int i = 0; i < 8; ++i) acc[i] = 0.f;
  for (int idx = tid; idx < 3072; idx += 256) {
    int i = idx / 96, r = idx % 96, c = r / 3, kk = r % 3;
    Als[(c * 3 + kk) * 32 + i] = w2_1[(oc0 + i) * 1536 + (c0 + c) * 3 + kk];
  }
  for (int idx = tid; idx < 6144; idx += 256) {
    int b = idx & 63, u = (idx >> 6) % 3, c = (idx >> 6) / 3;
    Bls[(c * 3 + u) * 64 + b] =
        relu(B2a[((c0 + c) * 3 + u) * 64 + b] + b1_1[c0 + c]);
  }
  __syncthreads();
  for (int c = 0; c < 32; ++c) {
    float bv[3];
#pragma unroll
    for (int u = 0; u < 3; ++u) bv[u] = Bls[(c * 3 + u) * 64 + lane];
    float av[3][8];
#pragma unroll
    for (int kk = 0; kk < 3; ++kk) {
      *(float4*)&av[kk][0] = *(const float4*)&Als[(c * 3 + kk) * 32 + wv * 8];
      *(float4*)&av[kk][4] = *(const float4*)&Als[(c * 3 + kk) * 32 + wv * 8 + 4];
    }
#pragma unroll
    for (int i = 0; i < 8; ++i)
#pragma unroll
      for (int kk = 0; kk < 3; ++kk) acc[i] += av[kk][i] * bv[kk];
  }
#pragma unroll
  for (int i = 0; i < 8; ++i)
    atomicAdd(&H1a[(oc0 + wv * 8 + i) * 64 + lane], acc[i]);
}

// ===== kE: fc, finalizing H1 inline (36 blocks x 256 thr, 4-wave split-o) ==
__global__ __launch_bounds__(256) void kE(
    const float* __restrict__ H1a, const float* __restrict__ b2_1,
    const float* __restrict__ H0a, const float* __restrict__ b2_0,
    const float* __restrict__ PDa, const float* __restrict__ bd0,
    const float* __restrict__ fcw, const float* __restrict__ fcb,
    float* __restrict__ out) {
  const int j = blockIdx.x, tid = threadIdx.x;
  const int lane = tid & 63, wv = tid >> 6;
  __shared__ float red[4][64];
  float partial = (wv == 0) ? fcb[j] : 0.f;
  for (int o = wv * 128; o < wv * 128 + 128; ++o) {
    float h0 = relu(relu(H0a[(o * 5 + 4) * 64 + lane] + b2_0[o]) +
                    PDa[(o * 5 + 4) * 64 + lane] + bd0[o]);
    float h1 = relu(relu(H1a[o * 64 + lane] + b2_1[o]) + h0);
    partial += fcw[j * 512 + o] * h1;
  }
  red[wv][lane] = partial;
  __syncthreads();
  if (wv == 0)
    out[lane * 36 + j] = red[0][lane] + red[1][lane] + red[2][lane] + red[3][lane];
}

extern "C" void kernel_launch(void* const* d_in, const int* in_sizes, int n_in,
                              void* d_out, int out_size, void* d_ws, size_t ws_size,
                              hipStream_t stream) {
  const float* x    = (const float*)d_in[0];
  const float* w1_0 = (const float*)d_in[4];
  const float* b1_0 = (const float*)d_in[5];
  const float* w2_0 = (const float*)d_in[6];
  const float* b2_0 = (const float*)d_in[7];
  const float* wd0  = (const float*)d_in[8];
  const float* bd0  = (const float*)d_in[9];
  const float* w1_1 = (const float*)d_in[10];
  const float* b1_1 = (const float*)d_in[11];
  const float* w2_1 = (const float*)d_in[12];
  const float* b2_1 = (const float*)d_in[13];
  const float* fcw  = (const float*)d_in[14];
  const float* fcb  = (const float*)d_in[15];
  float* out = (float*)d_out;

  float* B1a = (float*)d_ws;     // 512*11*64 = 360448
  float* PDa = B1a + 360448;     // 512*5*64  = 163840
  float* H0a = PDa + 163840;     // 512*5*64  = 163840
  float* B2a = H0a + 163840;     // 512*3*64  =  98304
  float* H1a = B2a + 98304;      // 512*64    =  32768
  // total 819200 floats = 3,276,800 B — zeroed every call (accumulators)
  hipMemsetAsync(d_ws, 0, 819200 * sizeof(float), stream);

  kA<<<384, 256, 0, stream>>>(x, w1_0, wd0, B1a, PDa);
  kB<<<256, 256, 0, stream>>>(B1a, b1_0, w2_0, H0a);
  kC<<<256, 256, 0, stream>>>(H0a, b2_0, PDa, bd0, w1_1, B2a);
  kD<<<256, 256, 0, stream>>>(B2a, b1_1, w2_1, H1a);
  kE<<<36, 256, 0, stream>>>(H1a, b2_1, H0a, b2_0, PDa, bd0, fcw, fcb, out);
}